// Round 10
// baseline (3393.107 us; speedup 1.0000x reference)
//
#include <hip/hip_runtime.h>

#define NINT  255
#define BM    16
#define PITCH 136            // activation row pitch in bf16 elems (128 + 8 pad)

typedef __bf16 bf16x8 __attribute__((ext_vector_type(8)));
typedef float  f32x4  __attribute__((ext_vector_type(4)));

#define MFMA(a, b, c) __builtin_amdgcn_mfma_f32_16x16x32_bf16((a), (b), (c), 0, 0, 0)

__device__ __forceinline__ unsigned short f2b(float f) {
    __bf16 b = (__bf16)f;
    return __builtin_bit_cast(unsigned short, b);
}

// softplus = ln2 * log2(1 + 2^(x*log2e)); guard only the overflow region
__device__ __forceinline__ float sp_f(float x) {
    float e = __builtin_amdgcn_exp2f(x * 1.4426950408889634f);
    float y = __builtin_amdgcn_logf(1.0f + e) * 0.6931471805599453f;
    return (x > 80.0f) ? x : y;
}

// tanh = 1 - 2/(2^(2x*log2e) + 1); saturates correctly at +-inf via v_exp/v_rcp
__device__ __forceinline__ float tanh_f(float x) {
    float e = __builtin_amdgcn_exp2f(x * 2.8853900817779268f);
    float r = __builtin_amdgcn_rcpf(e + 1.0f);
    return fmaf(-2.0f, r, 1.0f);
}

// ---- prep: swizzle W1/W2/W3 into MFMA fragment order (bf16) ----
// frag element e = ((n*4 + t)*64 + l)*8 + i  ->  W[k][col],  k = 32t + (l>>4)*8 + i,
// col = 16n + (l&15).
__global__ void prep_frags(const float* __restrict__ W1, const float* __restrict__ W2,
                           const float* __restrict__ W3,
                           unsigned short* __restrict__ W1f, unsigned short* __restrict__ W2f,
                           unsigned short* __restrict__ W3f) {
    const int e = blockIdx.x * 256 + threadIdx.x;   // 0 .. 131071
    const int i = e & 7;
    const int l = (e >> 3) & 63;
    const int t = (e >> 9) & 3;
    const int n = e >> 11;
    const int k = 32 * t + ((l >> 4) & 3) * 8 + i;
    const int c = l & 15;
    if (e < 16384) {
        W1f[e] = f2b(W1[k * 128 + 16 * n + c]);
        W2f[e] = f2b(W2[k * 128 + 16 * n + c]);
    }
    W3f[e] = f2b(W3[k * 1024 + 16 * n + c]);
}

// RK stage update for one jl (ST literal); h = 32*JL + h2wb
#define RK_UPDATE(ST, JL)                                                        \
{                                                                                \
    float znew;                                                                  \
    if (ST == 0)      { k1r[JL] = p; znew = zb[JL] + p * (1.0f/3.0f); }          \
    else if (ST == 1) { k2r[JL] = p; znew = zb[JL] + p - k1r[JL] * (1.0f/3.0f); }\
    else if (ST == 2) { k3r[JL] = p; znew = zb[JL] + k1r[JL] - k2r[JL] + p; }    \
    else { zb[JL] = fmaf(k1r[JL] + 3.0f*(k2r[JL] + k3r[JL]) + p, 0.125f, zb[JL]); znew = zb[JL]; } \
    if ((g & 1) == 0)                                                            \
        Zs[l15 * PITCH + 32 * JL + h2wb] = f2b(znew);                            \
}

// One RK stage. ST literal. mm1/mm2 on waves 0-7 (W1/W2 streamed through w12r);
// mm3+RK on all 16 waves: tiles {w, 16+w} from regs, {32+w, 48+w} from LDS.
#define STAGE_BODY(ST)                                                           \
{                                                                                \
    if (w < 8) {                                                                 \
        bf16x8 a0[4];                                                            \
        _Pragma("unroll") for (int t = 0; t < 4; ++t)                            \
            a0[t] = *(const bf16x8*)(Zs + l15 * PITCH + t * 32 + koff);          \
        f32x4 h1 = {b1r, b1r, b1r, b1r};                                         \
        _Pragma("unroll") for (int t = 0; t < 4; ++t)                            \
            h1 = MFMA(a0[t], w12r[t], h1);                                       \
        _Pragma("unroll") for (int t = 0; t < 4; ++t)                            \
            w12r[t] = w2v[(w * 4 + t) * 64 + l];        /* stream W2 in */       \
        _Pragma("unroll") for (int i = 0; i < 4; ++i)                            \
            H1s[(g * 4 + i) * PITCH + 16 * w + l15] = f2b(sp_f(h1[i]));          \
    }                                                                            \
    __syncthreads();                                                             \
    if (w < 8) {                                                                 \
        bf16x8 a1[4];                                                            \
        _Pragma("unroll") for (int t = 0; t < 4; ++t)                            \
            a1[t] = *(const bf16x8*)(H1s + l15 * PITCH + t * 32 + koff);         \
        f32x4 h2 = {b2r, b2r, b2r, b2r};                                         \
        _Pragma("unroll") for (int t = 0; t < 4; ++t)                            \
            h2 = MFMA(a1[t], w12r[t], h2);                                       \
        _Pragma("unroll") for (int t = 0; t < 4; ++t)                            \
            w12r[t] = w1v[(w * 4 + t) * 64 + l];        /* next stage's W1 */    \
        _Pragma("unroll") for (int i = 0; i < 4; ++i)                            \
            H2s[(g * 4 + i) * PITCH + 16 * w + l15] = f2b(sp_f(h2[i]));          \
    }                                                                            \
    __syncthreads();                                                             \
    {                                                                            \
        bf16x8 bfr[4];                                                           \
        _Pragma("unroll") for (int t = 0; t < 4; ++t)                            \
            bfr[t] = *(const bf16x8*)(H2s + l15 * PITCH + t * 32 + koff);        \
        f32x4 xdv;                                                               \
        if (ST == 0) xdv = xd0;                                                  \
        else if (ST == 1) { _Pragma("unroll") for (int i = 0; i < 4; ++i)        \
            xdv[i] = bB[i] + (tcv[i] + tdv[i] * (1.0f/3.0f)) * (1.0f/3.0f); }    \
        else if (ST == 2) { _Pragma("unroll") for (int i = 0; i < 4; ++i)        \
            xdv[i] = bB[i] + (tcv[i] + tdv[i] * (2.0f/3.0f)) * (2.0f/3.0f); }    \
        else { _Pragma("unroll") for (int i = 0; i < 4; ++i)                     \
            xdv[i] = bB[i] + tcv[i] + tdv[i];  xd0 = xdv; }                      \
        /* pair A: register tiles {w, 16+w} */                                   \
        {                                                                        \
            f32x4 acc0 = *(const f32x4*)&b3s[16 * w + 4 * g];                    \
            f32x4 acc1 = *(const f32x4*)&b3s[16 * (16 + w) + 4 * g];             \
            _Pragma("unroll") for (int t = 0; t < 4; ++t) {                      \
                acc0 = MFMA(w3g[0][t], bfr[t], acc0);                            \
                acc1 = MFMA(w3g[1][t], bfr[t], acc1);                            \
            }                                                                    \
            float p;                                                             \
            p = 0.0f;                                                            \
            _Pragma("unroll") for (int i = 0; i < 4; ++i)                        \
                p = fmaf(tanh_f(acc0[i]), xdv[i], p);                            \
            p += __shfl_xor(p, 16, 64);                                          \
            RK_UPDATE(ST, 0)                                                     \
            p = 0.0f;                                                            \
            _Pragma("unroll") for (int i = 0; i < 4; ++i)                        \
                p = fmaf(tanh_f(acc1[i]), xdv[i], p);                            \
            p += __shfl_xor(p, 16, 64);                                          \
            RK_UPDATE(ST, 1)                                                     \
        }                                                                        \
        /* pair B: LDS tiles {32+w, 48+w} (local indices w, 16+w) */             \
        {                                                                        \
            f32x4 acc0 = *(const f32x4*)&b3s[16 * (32 + w) + 4 * g];             \
            f32x4 acc1 = *(const f32x4*)&b3s[16 * (48 + w) + 4 * g];             \
            _Pragma("unroll") for (int t = 0; t < 4; ++t) {                      \
                acc0 = MFMA(w3lv[(w * 4 + t) * 64 + l], bfr[t], acc0);           \
                acc1 = MFMA(w3lv[((16 + w) * 4 + t) * 64 + l], bfr[t], acc1);    \
            }                                                                    \
            float p;                                                             \
            p = 0.0f;                                                            \
            _Pragma("unroll") for (int i = 0; i < 4; ++i)                        \
                p = fmaf(tanh_f(acc0[i]), xdv[i], p);                            \
            p += __shfl_xor(p, 16, 64);                                          \
            RK_UPDATE(ST, 2)                                                     \
            p = 0.0f;                                                            \
            _Pragma("unroll") for (int i = 0; i < 4; ++i)                        \
                p = fmaf(tanh_f(acc1[i]), xdv[i], p);                            \
            p += __shfl_xor(p, 16, 64);                                          \
            RK_UPDATE(ST, 3)                                                     \
        }                                                                        \
    }                                                                            \
    __syncthreads();                                                             \
}

__global__ __launch_bounds__(1024, 4)
void cde_mfma(const float* __restrict__ coeffs,
              const float* __restrict__ W_init, const float* __restrict__ b_init,
              const float* __restrict__ b1, const float* __restrict__ b2,
              const float* __restrict__ b3,
              const float* __restrict__ W_out, const float* __restrict__ b_out,
              const unsigned short* __restrict__ w1f, const unsigned short* __restrict__ w2f,
              const unsigned short* __restrict__ w3f,
              float* __restrict__ out)
{
    // LDS: 131072 + 3*4352 + 4096 + 2048 = 150,272 B
    __shared__ __align__(16) unsigned short W3l_lds[65536];   // 128 KB: W3 tiles 32..63
    __shared__ __align__(16) unsigned short Zs [BM * PITCH];
    __shared__ __align__(16) unsigned short H1s[BM * PITCH];
    __shared__ __align__(16) unsigned short H2s[BM * PITCH];
    __shared__ __align__(16) float b3s[1024];
    __shared__ __align__(16) float Outp[32][16];

    const int tid     = threadIdx.x;        // 0..1023
    const int rowbase = blockIdx.x * BM;
    const int l       = tid & 63;
    const int w       = tid >> 6;           // wave 0..15
    const int l15     = l & 15;
    const int g       = (l >> 4) & 3;
    const int hb      = g >> 1;
    const int koff    = g * 8;
    const int chB     = 4 * (g & 1);        // c-offset of this lane's 4 channels
    const int h2wb    = 2 * w + hb;         // h = 32*jl + h2wb

    // ---- one-time staging: W3 tiles 32..63 -> LDS (128 KB), b3 -> LDS ----
    for (int k4 = tid; k4 < 8192; k4 += 1024)
        ((uint4*)W3l_lds)[k4] = ((const uint4*)(w3f + 32 * 2048))[k4];
    b3s[tid] = b3[tid];

    // ---- per-wave register weights: W3 tiles {w, 16+w} ----
    const bf16x8* w1v = (const bf16x8*)w1f;
    const bf16x8* w2v = (const bf16x8*)w2f;
    const bf16x8* w3v = (const bf16x8*)w3f;
    bf16x8 w3g[2][4];
    #pragma unroll
    for (int jl = 0; jl < 2; ++jl)
        #pragma unroll
        for (int t = 0; t < 4; ++t)
            w3g[jl][t] = w3v[((16 * jl + w) * 4 + t) * 64 + l];

    // ---- W1/W2 stream buffer (waves 0-7): starts holding W1 ----
    bf16x8 w12r[4];
    float b1r = 0.0f, b2r = 0.0f;
    if (w < 8) {
        #pragma unroll
        for (int t = 0; t < 4; ++t)
            w12r[t] = w1v[(w * 4 + t) * 64 + l];
        b1r = b1[16 * w + l15];
        b2r = b2[16 * w + l15];
    }

    // ---- z0 = a[:,0] @ W_init + b_init ; lane state h = 32*jl + 2w + hb ----
    float zb[4], k1r[4], k2r[4], k3r[4];
    {
        const float* ap = coeffs + (size_t)(rowbase + l15) * (NINT * 32);
        float av[8];
        #pragma unroll
        for (int c = 0; c < 8; ++c) av[c] = ap[c];
        #pragma unroll
        for (int jl = 0; jl < 4; ++jl) {
            const int h = 32 * jl + h2wb;
            float z = b_init[h];
            #pragma unroll
            for (int c = 0; c < 8; ++c) z = fmaf(av[c], W_init[c * 128 + h], z);
            zb[jl] = z;
            if ((g & 1) == 0) Zs[l15 * PITCH + h] = f2b(z);
        }
    }

    // ---- X'(t) register state: this lane's 4 channels chB..chB+3 ----
    const float* cpx = coeffs + (size_t)(rowbase + l15) * (NINT * 32) + chB;
    f32x4 bB, tcv, tdv;
    f32x4 xd0 = *(const f32x4*)(cpx + 8);   // X'(0): interval 0, frac 0 -> b only

    const bf16x8* w3lv = (const bf16x8*)W3l_lds;
    __syncthreads();

    #pragma unroll 1
    for (int step = 0; step < NINT; ++step) {
        // load THIS interval's coeffs; first use is stage 1's xdv (a full stage away)
        const float* cc = cpx + step * 32;
        bB  = *(const f32x4*)(cc + 8);
        tcv = *(const f32x4*)(cc + 16);
        tdv = *(const f32x4*)(cc + 24);

        STAGE_BODY(0)
        STAGE_BODY(1)
        STAGE_BODY(2)
        STAGE_BODY(3)
    }

    // ---- epilogue: out = zT @ W_out + b_out ----
    if ((g & 1) == 0) {
        float prt = 0.0f;
        #pragma unroll
        for (int jl = 0; jl < 4; ++jl)
            prt = fmaf(zb[jl], W_out[32 * jl + h2wb], prt);
        Outp[h2wb][l15] = prt;
    }
    __syncthreads();
    if (tid < 16) {
        float s = b_out[0];
        #pragma unroll
        for (int p = 0; p < 32; ++p) s += Outp[p][tid];
        out[rowbase + tid] = s;
    }
}

extern "C" void kernel_launch(void* const* d_in, const int* in_sizes, int n_in,
                              void* d_out, int out_size, void* d_ws, size_t ws_size,
                              hipStream_t stream) {
    const float* coeffs = (const float*)d_in[0];
    const float* W_init = (const float*)d_in[1];
    const float* b_init = (const float*)d_in[2];
    const float* W1     = (const float*)d_in[3];
    const float* b1     = (const float*)d_in[4];
    const float* W2     = (const float*)d_in[5];
    const float* b2     = (const float*)d_in[6];
    const float* W3     = (const float*)d_in[7];
    const float* b3     = (const float*)d_in[8];
    const float* W_out  = (const float*)d_in[9];
    const float* b_out  = (const float*)d_in[10];
    float* outp = (float*)d_out;

    unsigned short* w1f = (unsigned short*)d_ws;            // 32 KB
    unsigned short* w2f = w1f + 16384;                      // 32 KB
    unsigned short* w3f = w2f + 16384;                      // 256 KB

    hipLaunchKernelGGL(prep_frags, dim3(512), dim3(256), 0, stream, W1, W2, W3, w1f, w2f, w3f);
    hipLaunchKernelGGL(cde_mfma, dim3(4096 / BM), dim3(1024), 0, stream,
                       coeffs, W_init, b_init, b1, b2, b3, W_out, b_out,
                       w1f, w2f, w3f, outp);
}

// Round 11
// 3069.170 us; speedup vs baseline: 1.1055x; 1.1055x over previous
//
#include <hip/hip_runtime.h>

#define NINT  255
#define BM    16
#define PITCH 136            // activation row pitch in bf16 elems (128 + 8 pad)

typedef __bf16 bf16x8 __attribute__((ext_vector_type(8)));
typedef float  f32x4  __attribute__((ext_vector_type(4)));

#define MFMA(a, b, c) __builtin_amdgcn_mfma_f32_16x16x32_bf16((a), (b), (c), 0, 0, 0)

__device__ __forceinline__ unsigned short f2b(float f) {
    __bf16 b = (__bf16)f;
    return __builtin_bit_cast(unsigned short, b);
}

// softplus = ln2 * log2(1 + 2^(x*log2e)); guard only the overflow region
__device__ __forceinline__ float sp_f(float x) {
    float e = __builtin_amdgcn_exp2f(x * 1.4426950408889634f);
    float y = __builtin_amdgcn_logf(1.0f + e) * 0.6931471805599453f;
    return (x > 80.0f) ? x : y;
}

// tanh = 1 - 2/(2^(2x*log2e) + 1); saturates correctly at +-inf via v_exp/v_rcp
__device__ __forceinline__ float tanh_f(float x) {
    float e = __builtin_amdgcn_exp2f(x * 2.8853900817779268f);
    float r = __builtin_amdgcn_rcpf(e + 1.0f);
    return fmaf(-2.0f, r, 1.0f);
}

// ---- prep: swizzle W1/W2/W3 into MFMA fragment order (bf16) ----
// frag element e = ((n*4 + t)*64 + l)*8 + i  ->  W[k][col],  k = 32t + (l>>4)*8 + i,
// col = 16n + (l&15).
__global__ void prep_frags(const float* __restrict__ W1, const float* __restrict__ W2,
                           const float* __restrict__ W3,
                           unsigned short* __restrict__ W1f, unsigned short* __restrict__ W2f,
                           unsigned short* __restrict__ W3f) {
    const int e = blockIdx.x * 256 + threadIdx.x;   // 0 .. 131071
    const int i = e & 7;
    const int l = (e >> 3) & 63;
    const int t = (e >> 9) & 3;
    const int n = e >> 11;
    const int k = 32 * t + ((l >> 4) & 3) * 8 + i;
    const int c = l & 15;
    if (e < 16384) {
        W1f[e] = f2b(W1[k * 128 + 16 * n + c]);
        W2f[e] = f2b(W2[k * 128 + 16 * n + c]);
    }
    W3f[e] = f2b(W3[k * 1024 + 16 * n + c]);
}

// RK stage update for one jl (ST literal); h = 32*JL + h2wb
#define RK_UPDATE(ST, JL)                                                        \
{                                                                                \
    float znew;                                                                  \
    if (ST == 0)      { k1r[JL] = p; znew = zb[JL] + p * (1.0f/3.0f); }          \
    else if (ST == 1) { k2r[JL] = p; znew = zb[JL] + p - k1r[JL] * (1.0f/3.0f); }\
    else if (ST == 2) { k3r[JL] = p; znew = zb[JL] + k1r[JL] - k2r[JL] + p; }    \
    else { zb[JL] = fmaf(k1r[JL] + 3.0f*(k2r[JL] + k3r[JL]) + p, 0.125f, zb[JL]); znew = zb[JL]; } \
    if ((g & 1) == 0)                                                            \
        Zs[l15 * PITCH + 32 * JL + h2wb] = f2b(znew);                            \
}

// One RK stage. ST literal. mm1/mm2 on waves 0-7 (W1/W2 streamed through w12r);
// mm3+RK on all 16 waves: tiles {w, 16+w} from regs, {32+w, 48+w} from LDS.
// X'(t) comes from the Xds LDS table (parity-buffered per step).
#define STAGE_BODY(ST)                                                           \
{                                                                                \
    if (w < 8) {                                                                 \
        bf16x8 a0[4];                                                            \
        _Pragma("unroll") for (int t = 0; t < 4; ++t)                            \
            a0[t] = *(const bf16x8*)(Zs + l15 * PITCH + t * 32 + koff);          \
        f32x4 h1 = {b1r, b1r, b1r, b1r};                                         \
        _Pragma("unroll") for (int t = 0; t < 4; ++t)                            \
            h1 = MFMA(a0[t], w12r[t], h1);                                       \
        _Pragma("unroll") for (int t = 0; t < 4; ++t)                            \
            w12r[t] = w2v[(w * 4 + t) * 64 + l];        /* stream W2 in */       \
        _Pragma("unroll") for (int i = 0; i < 4; ++i)                            \
            H1s[(g * 4 + i) * PITCH + 16 * w + l15] = f2b(sp_f(h1[i]));          \
    }                                                                            \
    __syncthreads();                                                             \
    if (w < 8) {                                                                 \
        bf16x8 a1[4];                                                            \
        _Pragma("unroll") for (int t = 0; t < 4; ++t)                            \
            a1[t] = *(const bf16x8*)(H1s + l15 * PITCH + t * 32 + koff);         \
        f32x4 h2 = {b2r, b2r, b2r, b2r};                                         \
        _Pragma("unroll") for (int t = 0; t < 4; ++t)                            \
            h2 = MFMA(a1[t], w12r[t], h2);                                       \
        _Pragma("unroll") for (int t = 0; t < 4; ++t)                            \
            w12r[t] = w1v[(w * 4 + t) * 64 + l];        /* next stage's W1 */    \
        _Pragma("unroll") for (int i = 0; i < 4; ++i)                            \
            H2s[(g * 4 + i) * PITCH + 16 * w + l15] = f2b(sp_f(h2[i]));          \
    }                                                                            \
    __syncthreads();                                                             \
    {                                                                            \
        bf16x8 bfr[4];                                                           \
        _Pragma("unroll") for (int t = 0; t < 4; ++t)                            \
            bfr[t] = *(const bf16x8*)(H2s + l15 * PITCH + t * 32 + koff);        \
        const f32x4 xdv = *(const f32x4*)&Xds[par][ST][l15][chB];                \
        /* pair A: register tiles {w, 16+w} */                                   \
        {                                                                        \
            f32x4 acc0 = *(const f32x4*)&b3s[16 * w + 4 * g];                    \
            f32x4 acc1 = *(const f32x4*)&b3s[16 * (16 + w) + 4 * g];             \
            _Pragma("unroll") for (int t = 0; t < 4; ++t) {                      \
                acc0 = MFMA(w3g[0][t], bfr[t], acc0);                            \
                acc1 = MFMA(w3g[1][t], bfr[t], acc1);                            \
            }                                                                    \
            float p;                                                             \
            p = 0.0f;                                                            \
            _Pragma("unroll") for (int i = 0; i < 4; ++i)                        \
                p = fmaf(tanh_f(acc0[i]), xdv[i], p);                            \
            p += __shfl_xor(p, 16, 64);                                          \
            RK_UPDATE(ST, 0)                                                     \
            p = 0.0f;                                                            \
            _Pragma("unroll") for (int i = 0; i < 4; ++i)                        \
                p = fmaf(tanh_f(acc1[i]), xdv[i], p);                            \
            p += __shfl_xor(p, 16, 64);                                          \
            RK_UPDATE(ST, 1)                                                     \
        }                                                                        \
        /* pair B: LDS tiles {32+w, 48+w} (local indices w, 16+w) */             \
        {                                                                        \
            f32x4 acc0 = *(const f32x4*)&b3s[16 * (32 + w) + 4 * g];             \
            f32x4 acc1 = *(const f32x4*)&b3s[16 * (48 + w) + 4 * g];             \
            _Pragma("unroll") for (int t = 0; t < 4; ++t) {                      \
                acc0 = MFMA(w3lv[(w * 4 + t) * 64 + l], bfr[t], acc0);           \
                acc1 = MFMA(w3lv[((16 + w) * 4 + t) * 64 + l], bfr[t], acc1);    \
            }                                                                    \
            float p;                                                             \
            p = 0.0f;                                                            \
            _Pragma("unroll") for (int i = 0; i < 4; ++i)                        \
                p = fmaf(tanh_f(acc0[i]), xdv[i], p);                            \
            p += __shfl_xor(p, 16, 64);                                          \
            RK_UPDATE(ST, 2)                                                     \
            p = 0.0f;                                                            \
            _Pragma("unroll") for (int i = 0; i < 4; ++i)                        \
                p = fmaf(tanh_f(acc1[i]), xdv[i], p);                            \
            p += __shfl_xor(p, 16, 64);                                          \
            RK_UPDATE(ST, 3)                                                     \
        }                                                                        \
    }                                                                            \
    __syncthreads();                                                             \
}

__global__ __launch_bounds__(1024, 4)
void cde_mfma(const float* __restrict__ coeffs,
              const float* __restrict__ W_init, const float* __restrict__ b_init,
              const float* __restrict__ b1, const float* __restrict__ b2,
              const float* __restrict__ b3,
              const float* __restrict__ W_out, const float* __restrict__ b_out,
              const unsigned short* __restrict__ w1f, const unsigned short* __restrict__ w2f,
              const unsigned short* __restrict__ w3f,
              float* __restrict__ out)
{
    // LDS: 131072 + 3*4352 + 4096 + 4096 + 2048 = 154,368 B
    __shared__ __align__(16) unsigned short W3l_lds[65536];   // 128 KB: W3 tiles 32..63
    __shared__ __align__(16) unsigned short Zs [BM * PITCH];
    __shared__ __align__(16) unsigned short H1s[BM * PITCH];
    __shared__ __align__(16) unsigned short H2s[BM * PITCH];
    __shared__ __align__(16) float b3s[1024];
    __shared__ __align__(16) float Xds[2][4][16][8];          // parity x stage x batch x c
    __shared__ __align__(16) float Outp[32][16];

    const int tid     = threadIdx.x;        // 0..1023
    const int rowbase = blockIdx.x * BM;
    const int l       = tid & 63;
    const int w       = tid >> 6;           // wave 0..15
    const int l15     = l & 15;
    const int g       = (l >> 4) & 3;
    const int hb      = g >> 1;
    const int koff    = g * 8;
    const int chB     = 4 * (g & 1);        // c-offset of this lane's 4 channels
    const int h2wb    = 2 * w + hb;         // h = 32*jl + h2wb

    // ---- one-time staging: W3 tiles 32..63 -> LDS (128 KB), b3 -> LDS ----
    for (int k4 = tid; k4 < 8192; k4 += 1024)
        ((uint4*)W3l_lds)[k4] = ((const uint4*)(w3f + 32 * 2048))[k4];
    b3s[tid] = b3[tid];

    // ---- per-wave register weights: W3 tiles {w, 16+w} ----
    const bf16x8* w1v = (const bf16x8*)w1f;
    const bf16x8* w2v = (const bf16x8*)w2f;
    const bf16x8* w3v = (const bf16x8*)w3f;
    bf16x8 w3g[2][4];
    #pragma unroll
    for (int jl = 0; jl < 2; ++jl)
        #pragma unroll
        for (int t = 0; t < 4; ++t)
            w3g[jl][t] = w3v[((16 * jl + w) * 4 + t) * 64 + l];

    // ---- W1/W2 stream buffer (waves 0-7): starts holding W1 ----
    bf16x8 w12r[4];
    float b1r = 0.0f, b2r = 0.0f;
    if (w < 8) {
        #pragma unroll
        for (int t = 0; t < 4; ++t)
            w12r[t] = w1v[(w * 4 + t) * 64 + l];
        b1r = b1[16 * w + l15];
        b2r = b2[16 * w + l15];
    }

    // ---- z0 = a[:,0] @ W_init + b_init ; lane state h = 32*jl + 2w + hb ----
    float zb[4], k1r[4], k2r[4], k3r[4];
    {
        const float* ap = coeffs + (size_t)(rowbase + l15) * (NINT * 32);
        float av[8];
        #pragma unroll
        for (int c = 0; c < 8; ++c) av[c] = ap[c];
        #pragma unroll
        for (int jl = 0; jl < 4; ++jl) {
            const int h = 32 * jl + h2wb;
            float z = b_init[h];
            #pragma unroll
            for (int c = 0; c < 8; ++c) z = fmaf(av[c], W_init[c * 128 + h], z);
            zb[jl] = z;
            if ((g & 1) == 0) Zs[l15 * PITCH + h] = f2b(z);
        }
    }

    const bf16x8* w3lv = (const bf16x8*)W3l_lds;
    __syncthreads();

    #pragma unroll 1
    for (int step = 0; step < NINT; ++step) {
        const int par = step & 1;
        // ---- X'(t) for the 4 stage times of this step -> Xds[par] ----
        // Safe without an extra barrier: first read is in stage 0's mm3,
        // which is 2 barriers after this write; last read of Xds[par] was
        // step-2 (many barriers ago).
        if (tid < 128) {
            const int m = tid >> 3, c = tid & 7;
            const float* cp = coeffs + (size_t)(rowbase + m) * (NINT * 32);
            float s1;
            if (step == 0) s1 = cp[8 + c];
            else {
                const int i0 = (step - 1) * 32;
                s1 = cp[i0 + 8 + c] + cp[i0 + 16 + c] + cp[i0 + 24 + c];
            }
            const int ik = step * 32;
            const float bB = cp[ik + 8 + c];
            const float tc = cp[ik + 16 + c];
            const float td = cp[ik + 24 + c];
            Xds[par][0][m][c] = s1;
            Xds[par][1][m][c] = bB + (tc + td * (1.0f/3.0f)) * (1.0f/3.0f);
            Xds[par][2][m][c] = bB + (tc + td * (2.0f/3.0f)) * (2.0f/3.0f);
            Xds[par][3][m][c] = bB + tc + td;
        }

        STAGE_BODY(0)
        STAGE_BODY(1)
        STAGE_BODY(2)
        STAGE_BODY(3)
    }

    // ---- epilogue: out = zT @ W_out + b_out ----
    if ((g & 1) == 0) {
        float prt = 0.0f;
        #pragma unroll
        for (int jl = 0; jl < 4; ++jl)
            prt = fmaf(zb[jl], W_out[32 * jl + h2wb], prt);
        Outp[h2wb][l15] = prt;
    }
    __syncthreads();
    if (tid < 16) {
        float s = b_out[0];
        #pragma unroll
        for (int p = 0; p < 32; ++p) s += Outp[p][tid];
        out[rowbase + tid] = s;
    }
}

extern "C" void kernel_launch(void* const* d_in, const int* in_sizes, int n_in,
                              void* d_out, int out_size, void* d_ws, size_t ws_size,
                              hipStream_t stream) {
    const float* coeffs = (const float*)d_in[0];
    const float* W_init = (const float*)d_in[1];
    const float* b_init = (const float*)d_in[2];
    const float* W1     = (const float*)d_in[3];
    const float* b1     = (const float*)d_in[4];
    const float* W2     = (const float*)d_in[5];
    const float* b2     = (const float*)d_in[6];
    const float* W3     = (const float*)d_in[7];
    const float* b3     = (const float*)d_in[8];
    const float* W_out  = (const float*)d_in[9];
    const float* b_out  = (const float*)d_in[10];
    float* outp = (float*)d_out;

    unsigned short* w1f = (unsigned short*)d_ws;            // 32 KB
    unsigned short* w2f = w1f + 16384;                      // 32 KB
    unsigned short* w3f = w2f + 16384;                      // 256 KB

    hipLaunchKernelGGL(prep_frags, dim3(512), dim3(256), 0, stream, W1, W2, W3, w1f, w2f, w3f);
    hipLaunchKernelGGL(cde_mfma, dim3(4096 / BM), dim3(1024), 0, stream,
                       coeffs, W_init, b_init, b1, b2, b3, W_out, b_out,
                       w1f, w2f, w3f, outp);
}

// Round 12
// 2907.201 us; speedup vs baseline: 1.1671x; 1.0557x over previous
//
#include <hip/hip_runtime.h>

#define NINT  255
#define BM    16
#define PITCH 136            // activation row pitch in bf16 elems (128 + 8 pad)

typedef __bf16 bf16x8 __attribute__((ext_vector_type(8)));
typedef float  f32x4  __attribute__((ext_vector_type(4)));

#define MFMA(a, b, c) __builtin_amdgcn_mfma_f32_16x16x32_bf16((a), (b), (c), 0, 0, 0)

__device__ __forceinline__ unsigned short f2b(float f) {
    __bf16 b = (__bf16)f;
    return __builtin_bit_cast(unsigned short, b);
}

// softplus = ln2 * log2(1 + 2^(x*log2e)); guard only the overflow region
__device__ __forceinline__ float sp_f(float x) {
    float e = __builtin_amdgcn_exp2f(x * 1.4426950408889634f);
    float y = __builtin_amdgcn_logf(1.0f + e) * 0.6931471805599453f;
    return (x > 80.0f) ? x : y;
}

// tanh = 1 - 2/(2^(2x*log2e) + 1); saturates correctly at +-inf via v_exp/v_rcp
__device__ __forceinline__ float tanh_f(float x) {
    float e = __builtin_amdgcn_exp2f(x * 2.8853900817779268f);
    float r = __builtin_amdgcn_rcpf(e + 1.0f);
    return fmaf(-2.0f, r, 1.0f);
}

// ---- prep: swizzle W1/W2/W3 into MFMA fragment order (bf16) ----
// frag element e = ((n*4 + t)*64 + l)*8 + i  ->  W[k][col],  k = 32t + (l>>4)*8 + i,
// col = 16n + (l&15).
__global__ void prep_frags(const float* __restrict__ W1, const float* __restrict__ W2,
                           const float* __restrict__ W3,
                           unsigned short* __restrict__ W1f, unsigned short* __restrict__ W2f,
                           unsigned short* __restrict__ W3f) {
    const int e = blockIdx.x * 256 + threadIdx.x;   // 0 .. 131071
    const int i = e & 7;
    const int l = (e >> 3) & 63;
    const int t = (e >> 9) & 3;
    const int n = e >> 11;
    const int k = 32 * t + ((l >> 4) & 3) * 8 + i;
    const int c = l & 15;
    if (e < 16384) {
        W1f[e] = f2b(W1[k * 128 + 16 * n + c]);
        W2f[e] = f2b(W2[k * 128 + 16 * n + c]);
    }
    W3f[e] = f2b(W3[k * 1024 + 16 * n + c]);
}

// RK stage update for one tile-slot T (ST literal); h = 2*TILE + hb
#define RK_UPDATE(ST, T, TILE)                                                   \
{                                                                                \
    float znew;                                                                  \
    if (ST == 0)      { k1r[T] = p; znew = zb[T] + p * (1.0f/3.0f); }            \
    else if (ST == 1) { k2r[T] = p; znew = zb[T] + p - k1r[T] * (1.0f/3.0f); }   \
    else if (ST == 2) { k3r[T] = p; znew = zb[T] + k1r[T] - k2r[T] + p; }        \
    else { zb[T] = fmaf(k1r[T] + 3.0f*(k2r[T] + k3r[T]) + p, 0.125f, zb[T]); znew = zb[T]; } \
    if ((g & 1) == 0)                                                            \
        Zs[l15 * PITCH + 2 * (TILE) + hb] = f2b(znew);                           \
}

// One RK stage. ST literal. mm1/mm2 on waves 0-7 (W1/W2 streamed through w12r);
// mm3+RK on all 12 waves: tile = 12*t + w, t < ntl (6 for w<4, else 5).
// Tiles <32 from registers (w3g[t]), tiles >=32 from LDS.
#define STAGE_BODY(ST)                                                           \
{                                                                                \
    if (w < 8) {                                                                 \
        bf16x8 a0[4];                                                            \
        _Pragma("unroll") for (int t = 0; t < 4; ++t)                            \
            a0[t] = *(const bf16x8*)(Zs + l15 * PITCH + t * 32 + koff);          \
        f32x4 h1 = {b1r, b1r, b1r, b1r};                                         \
        _Pragma("unroll") for (int t = 0; t < 4; ++t)                            \
            h1 = MFMA(a0[t], w12r[t], h1);                                       \
        _Pragma("unroll") for (int t = 0; t < 4; ++t)                            \
            w12r[t] = w2v[(w * 4 + t) * 64 + l];        /* stream W2 in */       \
        _Pragma("unroll") for (int i = 0; i < 4; ++i)                            \
            H1s[(g * 4 + i) * PITCH + 16 * w + l15] = f2b(sp_f(h1[i]));          \
    }                                                                            \
    __syncthreads();                                                             \
    if (w < 8) {                                                                 \
        bf16x8 a1[4];                                                            \
        _Pragma("unroll") for (int t = 0; t < 4; ++t)                            \
            a1[t] = *(const bf16x8*)(H1s + l15 * PITCH + t * 32 + koff);         \
        f32x4 h2 = {b2r, b2r, b2r, b2r};                                         \
        _Pragma("unroll") for (int t = 0; t < 4; ++t)                            \
            h2 = MFMA(a1[t], w12r[t], h2);                                       \
        _Pragma("unroll") for (int t = 0; t < 4; ++t)                            \
            w12r[t] = w1v[(w * 4 + t) * 64 + l];        /* next stage's W1 */    \
        _Pragma("unroll") for (int i = 0; i < 4; ++i)                            \
            H2s[(g * 4 + i) * PITCH + 16 * w + l15] = f2b(sp_f(h2[i]));          \
    }                                                                            \
    __syncthreads();                                                             \
    {                                                                            \
        bf16x8 bfr[4];                                                           \
        _Pragma("unroll") for (int t = 0; t < 4; ++t)                            \
            bfr[t] = *(const bf16x8*)(H2s + l15 * PITCH + t * 32 + koff);        \
        const f32x4 xdv = *(const f32x4*)&Xds[par][ST][l15][chB];                \
        _Pragma("unroll")                                                        \
        for (int t = 0; t < 6; ++t) {                                            \
            if (t < ntl) {                                                       \
                const int tile = 12 * t + w;                                     \
                f32x4 acc = *(const f32x4*)&b3s[16 * tile + 4 * g];              \
                if (tile < 32) {                                                 \
                    _Pragma("unroll") for (int tt = 0; tt < 4; ++tt)             \
                        acc = MFMA(w3g[t][tt], bfr[tt], acc);                    \
                } else {                                                         \
                    _Pragma("unroll") for (int tt = 0; tt < 4; ++tt)             \
                        acc = MFMA(w3lv[((tile - 32) * 4 + tt) * 64 + l], bfr[tt], acc); \
                }                                                                \
                float p = 0.0f;                                                  \
                _Pragma("unroll") for (int i = 0; i < 4; ++i)                    \
                    p = fmaf(tanh_f(acc[i]), xdv[i], p);                         \
                p += __shfl_xor(p, 16, 64);                                      \
                RK_UPDATE(ST, t, tile)                                           \
            }                                                                    \
        }                                                                        \
    }                                                                            \
    __syncthreads();                                                             \
}

__global__ __launch_bounds__(768, 3)
void cde_mfma(const float* __restrict__ coeffs,
              const float* __restrict__ W_init, const float* __restrict__ b_init,
              const float* __restrict__ b1, const float* __restrict__ b2,
              const float* __restrict__ b3,
              const float* __restrict__ W_out, const float* __restrict__ b_out,
              const unsigned short* __restrict__ w1f, const unsigned short* __restrict__ w2f,
              const unsigned short* __restrict__ w3f,
              float* __restrict__ out)
{
    // LDS: 131072 + 3*4352 + 4096 + 4096 + 1536 = 153,856 B
    __shared__ __align__(16) unsigned short W3l_lds[65536];   // 128 KB: W3 tiles 32..63
    __shared__ __align__(16) unsigned short Zs [BM * PITCH];
    __shared__ __align__(16) unsigned short H1s[BM * PITCH];
    __shared__ __align__(16) unsigned short H2s[BM * PITCH];
    __shared__ __align__(16) float b3s[1024];
    __shared__ __align__(16) float Xds[2][4][16][8];          // parity x stage x batch x c
    __shared__ __align__(16) float Outp[24][16];

    const int tid     = threadIdx.x;        // 0..767
    const int rowbase = blockIdx.x * BM;
    const int l       = tid & 63;
    const int w       = tid >> 6;           // wave 0..11
    const int l15     = l & 15;
    const int g       = (l >> 4) & 3;
    const int hb      = g >> 1;
    const int koff    = g * 8;
    const int chB     = 4 * (g & 1);        // c-offset of this lane's 4 channels
    const int ntl     = (w < 4) ? 6 : 5;    // mm3 tiles this wave

    // ---- one-time staging: W3 tiles 32..63 -> LDS (128 KB), b3 -> LDS ----
    for (int k4 = tid; k4 < 8192; k4 += 768)
        ((uint4*)W3l_lds)[k4] = ((const uint4*)(w3f + 32 * 2048))[k4];
    for (int k = tid; k < 1024; k += 768) b3s[k] = b3[k];

    // ---- per-wave register weights: W3 tiles {w, 12+w, 24+w} (24+w used iff <32) ----
    const bf16x8* w1v = (const bf16x8*)w1f;
    const bf16x8* w2v = (const bf16x8*)w2f;
    const bf16x8* w3v = (const bf16x8*)w3f;
    bf16x8 w3g[3][4];
    #pragma unroll
    for (int t = 0; t < 3; ++t)
        #pragma unroll
        for (int tt = 0; tt < 4; ++tt)
            w3g[t][tt] = w3v[((12 * t + w) * 4 + tt) * 64 + l];

    // ---- W1/W2 stream buffer (waves 0-7): starts holding W1 ----
    bf16x8 w12r[4];
    float b1r = 0.0f, b2r = 0.0f;
    if (w < 8) {
        #pragma unroll
        for (int t = 0; t < 4; ++t)
            w12r[t] = w1v[(w * 4 + t) * 64 + l];
        b1r = b1[16 * w + l15];
        b2r = b2[16 * w + l15];
    }

    // ---- z0 = a[:,0] @ W_init + b_init ; lane state h = 2*(12t+w) + hb ----
    float zb[6], k1r[6], k2r[6], k3r[6];
    {
        const float* ap = coeffs + (size_t)(rowbase + l15) * (NINT * 32);
        float av[8];
        #pragma unroll
        for (int c = 0; c < 8; ++c) av[c] = ap[c];
        #pragma unroll
        for (int t = 0; t < 6; ++t) {
            if (t < ntl) {
                const int h = 2 * (12 * t + w) + hb;
                float z = b_init[h];
                #pragma unroll
                for (int c = 0; c < 8; ++c) z = fmaf(av[c], W_init[c * 128 + h], z);
                zb[t] = z;
                if ((g & 1) == 0) Zs[l15 * PITCH + h] = f2b(z);
            }
        }
    }

    const bf16x8* w3lv = (const bf16x8*)W3l_lds;
    __syncthreads();

    #pragma unroll 1
    for (int step = 0; step < NINT; ++step) {
        const int par = step & 1;
        // ---- X'(t) for the 4 stage times of this step -> Xds[par] ----
        // First read of Xds[par] is stage-0 mm3, two barriers after this write;
        // the previous-parity buffer was last read before the final barrier of
        // the previous step, so no extra barrier is needed.
        if (tid < 128) {
            const int m = tid >> 3, c = tid & 7;
            const float* cp = coeffs + (size_t)(rowbase + m) * (NINT * 32);
            float s1;
            if (step == 0) s1 = cp[8 + c];
            else {
                const int i0 = (step - 1) * 32;
                s1 = cp[i0 + 8 + c] + cp[i0 + 16 + c] + cp[i0 + 24 + c];
            }
            const int ik = step * 32;
            const float bB = cp[ik + 8 + c];
            const float tc = cp[ik + 16 + c];
            const float td = cp[ik + 24 + c];
            Xds[par][0][m][c] = s1;
            Xds[par][1][m][c] = bB + (tc + td * (1.0f/3.0f)) * (1.0f/3.0f);
            Xds[par][2][m][c] = bB + (tc + td * (2.0f/3.0f)) * (2.0f/3.0f);
            Xds[par][3][m][c] = bB + tc + td;
        }

        STAGE_BODY(0)
        STAGE_BODY(1)
        STAGE_BODY(2)
        STAGE_BODY(3)
    }

    // ---- epilogue: out = zT @ W_out + b_out ----
    if ((g & 1) == 0) {
        float prt = 0.0f;
        #pragma unroll
        for (int t = 0; t < 6; ++t)
            if (t < ntl)
                prt = fmaf(zb[t], W_out[2 * (12 * t + w) + hb], prt);
        Outp[2 * w + hb][l15] = prt;
    }
    __syncthreads();
    if (tid < 16) {
        float s = b_out[0];
        #pragma unroll
        for (int p = 0; p < 24; ++p) s += Outp[p][tid];
        out[rowbase + tid] = s;
    }
}

extern "C" void kernel_launch(void* const* d_in, const int* in_sizes, int n_in,
                              void* d_out, int out_size, void* d_ws, size_t ws_size,
                              hipStream_t stream) {
    const float* coeffs = (const float*)d_in[0];
    const float* W_init = (const float*)d_in[1];
    const float* b_init = (const float*)d_in[2];
    const float* W1     = (const float*)d_in[3];
    const float* b1     = (const float*)d_in[4];
    const float* W2     = (const float*)d_in[5];
    const float* b2     = (const float*)d_in[6];
    const float* W3     = (const float*)d_in[7];
    const float* b3     = (const float*)d_in[8];
    const float* W_out  = (const float*)d_in[9];
    const float* b_out  = (const float*)d_in[10];
    float* outp = (float*)d_out;

    unsigned short* w1f = (unsigned short*)d_ws;            // 32 KB
    unsigned short* w2f = w1f + 16384;                      // 32 KB
    unsigned short* w3f = w2f + 16384;                      // 256 KB

    hipLaunchKernelGGL(prep_frags, dim3(512), dim3(256), 0, stream, W1, W2, W3, w1f, w2f, w3f);
    hipLaunchKernelGGL(cde_mfma, dim3(4096 / BM), dim3(768), 0, stream,
                       coeffs, W_init, b_init, b1, b2, b3, W_out, b_out,
                       w1f, w2f, w3f, outp);
}

// Round 13
// 2546.354 us; speedup vs baseline: 1.3325x; 1.1417x over previous
//
#include <hip/hip_runtime.h>

#define NINT  255
#define BM    16
#define PITCH 136            // activation row pitch in bf16 elems (128 + 8 pad)

typedef __bf16 bf16x8 __attribute__((ext_vector_type(8)));
typedef float  f32x4  __attribute__((ext_vector_type(4)));

#define MFMA(a, b, c) __builtin_amdgcn_mfma_f32_16x16x32_bf16((a), (b), (c), 0, 0, 0)

__device__ __forceinline__ unsigned short f2b(float f) {
    __bf16 b = (__bf16)f;
    return __builtin_bit_cast(unsigned short, b);
}

// softplus = ln2 * log2(1 + 2^(x*log2e)); guard only the overflow region
__device__ __forceinline__ float sp_f(float x) {
    float e = __builtin_amdgcn_exp2f(x * 1.4426950408889634f);
    float y = __builtin_amdgcn_logf(1.0f + e) * 0.6931471805599453f;
    return (x > 80.0f) ? x : y;
}

// tanh = 1 - 2/(2^(2x*log2e) + 1); saturates correctly at +-inf via v_exp/v_rcp
__device__ __forceinline__ float tanh_f(float x) {
    float e = __builtin_amdgcn_exp2f(x * 2.8853900817779268f);
    float r = __builtin_amdgcn_rcpf(e + 1.0f);
    return fmaf(-2.0f, r, 1.0f);
}

// ---- prep: swizzle W1/W2/W3 into MFMA fragment order (bf16) ----
// frag element e = ((n*4 + t)*64 + l)*8 + i  ->  W[k][col],  k = 32t + (l>>4)*8 + i,
// col = 16n + (l&15).
__global__ void prep_frags(const float* __restrict__ W1, const float* __restrict__ W2,
                           const float* __restrict__ W3,
                           unsigned short* __restrict__ W1f, unsigned short* __restrict__ W2f,
                           unsigned short* __restrict__ W3f) {
    const int e = blockIdx.x * 256 + threadIdx.x;   // 0 .. 131071
    const int i = e & 7;
    const int l = (e >> 3) & 63;
    const int t = (e >> 9) & 3;
    const int n = e >> 11;
    const int k = 32 * t + ((l >> 4) & 3) * 8 + i;
    const int c = l & 15;
    if (e < 16384) {
        W1f[e] = f2b(W1[k * 128 + 16 * n + c]);
        W2f[e] = f2b(W2[k * 128 + 16 * n + c]);
    }
    W3f[e] = f2b(W3[k * 1024 + 16 * n + c]);
}

// One RK stage: mm1 -> mm2 -> mm3(+tanh+contract+RK update). ST is a literal.
#define STAGE_BODY(ST, XD)                                                       \
{                                                                                \
    bf16x8 a0[4];                                                                \
    _Pragma("unroll")                                                            \
    for (int t = 0; t < 4; ++t)                                                  \
        a0[t] = *(const bf16x8*)(Zs + batch * PITCH + t * 32 + koff);            \
    f32x4 h1 = {b1r, b1r, b1r, b1r};                                             \
    _Pragma("unroll")                                                            \
    for (int t = 0; t < 4; ++t) h1 = MFMA(a0[t], w1r[t], h1);                    \
    _Pragma("unroll")                                                            \
    for (int i = 0; i < 4; ++i)                                                  \
        H1s[(g * 4 + i) * PITCH + 16 * w + batch] = f2b(sp_f(h1[i]));            \
    __syncthreads();                                                             \
    bf16x8 a1[4];                                                                \
    _Pragma("unroll")                                                            \
    for (int t = 0; t < 4; ++t)                                                  \
        a1[t] = *(const bf16x8*)(H1s + batch * PITCH + t * 32 + koff);           \
    f32x4 h2 = {b2r, b2r, b2r, b2r};                                             \
    _Pragma("unroll")                                                            \
    for (int t = 0; t < 4; ++t) h2 = MFMA(a1[t], w2r[t], h2);                    \
    _Pragma("unroll")                                                            \
    for (int i = 0; i < 4; ++i)                                                  \
        H2s[(g * 4 + i) * PITCH + 16 * w + batch] = f2b(sp_f(h2[i]));            \
    __syncthreads();                                                             \
    bf16x8 bfr[4];                                                               \
    _Pragma("unroll")                                                            \
    for (int t = 0; t < 4; ++t)                                                  \
        bfr[t] = *(const bf16x8*)(H2s + batch * PITCH + t * 32 + koff);          \
    f32x4 acc[8];                                                                \
    _Pragma("unroll")                                                            \
    for (int jl = 0; jl < 4; ++jl) {                                             \
        acc[jl] = MFMA(w3g[jl][0], bfr[0], b3r8[jl]);                            \
        _Pragma("unroll")                                                        \
        for (int t = 1; t < 4; ++t) acc[jl] = MFMA(w3g[jl][t], bfr[t], acc[jl]); \
    }                                                                            \
    _Pragma("unroll")                                                            \
    for (int jl = 4; jl < 8; ++jl) {                                             \
        acc[jl] = MFMA(w3rv[(((jl - 4) * 8 + w) * 4 + 0) * 64 + l], bfr[0], b3r8[jl]); \
        _Pragma("unroll")                                                        \
        for (int t = 1; t < 4; ++t)                                              \
            acc[jl] = MFMA(w3rv[(((jl - 4) * 8 + w) * 4 + t) * 64 + l], bfr[t], acc[jl]); \
    }                                                                            \
    _Pragma("unroll")                                                            \
    for (int jl = 0; jl < 8; ++jl) {                                             \
        float p = 0.0f;                                                          \
        _Pragma("unroll")                                                        \
        for (int i = 0; i < 4; ++i) p = fmaf(tanh_f(acc[jl][i]), (XD)[i], p);    \
        p += __shfl_xor(p, 16, 64);                                              \
        float znew;                                                              \
        if (ST == 0)      { k1r[jl] = p; znew = zb[jl] + p * (1.0f/3.0f); }      \
        else if (ST == 1) { k2r[jl] = p; znew = zb[jl] + p - k1r[jl] * (1.0f/3.0f); } \
        else if (ST == 2) { k3r[jl] = p; znew = zb[jl] + k1r[jl] - k2r[jl] + p; } \
        else { zb[jl] = fmaf(k1r[jl] + 3.0f*(k2r[jl] + k3r[jl]) + p, 0.125f, zb[jl]); znew = zb[jl]; } \
        if ((g & 1) == 0)                                                        \
            Zs[batch * PITCH + 16 * jl + 2 * w + hb] = f2b(znew);                \
    }                                                                            \
    __syncthreads();                                                             \
}

__global__ __launch_bounds__(512, 2)
void cde_mfma(const float* __restrict__ coeffs,
              const float* __restrict__ W_init, const float* __restrict__ b_init,
              const float* __restrict__ b1, const float* __restrict__ b2,
              const float* __restrict__ b3,
              const float* __restrict__ W_out, const float* __restrict__ b_out,
              const unsigned short* __restrict__ w1f, const unsigned short* __restrict__ w2f,
              const unsigned short* __restrict__ w3f,
              float* __restrict__ out)
{
    // LDS: 131072 + 3*4352 + 1024 = 145152 B
    __shared__ __align__(16) unsigned short W3r_lds[65536];   // 128 KB: W3 tiles 32..63
    __shared__ __align__(16) unsigned short Zs [BM * PITCH];
    __shared__ __align__(16) unsigned short H1s[BM * PITCH];
    __shared__ __align__(16) unsigned short H2s[BM * PITCH];
    __shared__ __align__(16) float Outp[16][16];

    const int tid     = threadIdx.x;        // 0..511
    const int rowbase = blockIdx.x * BM;
    const int l       = tid & 63;
    const int w       = tid >> 6;           // wave 0..7
    const int batch   = l & 15;
    const int g       = (l >> 4) & 3;
    const int hb      = g >> 1;             // which of the tile's 2 h values
    const int chB     = 4 * (g & 1);        // c-offset of this lane's 4 channels
    const int koff    = g * 8;

    // ---- one-time: W3 tiles 32..63 -> LDS (128 KB) ----
    for (int k4 = tid; k4 < 8192; k4 += 512)
        ((uint4*)W3r_lds)[k4] = ((const uint4*)(w3f + 32 * 2048))[k4];

    // ---- per-wave weight fragments + biases in registers ----
    const bf16x8* w1v = (const bf16x8*)w1f;
    const bf16x8* w2v = (const bf16x8*)w2f;
    const bf16x8* w3v = (const bf16x8*)w3f;
    bf16x8 w1r[4], w2r[4], w3g[4][4];
    #pragma unroll
    for (int t = 0; t < 4; ++t) {
        w1r[t] = w1v[(w * 4 + t) * 64 + l];
        w2r[t] = w2v[(w * 4 + t) * 64 + l];
    }
    #pragma unroll
    for (int jl = 0; jl < 4; ++jl)
        #pragma unroll
        for (int t = 0; t < 4; ++t)
            w3g[jl][t] = w3v[((8 * jl + w) * 4 + t) * 64 + l];

    const float b1r = b1[16 * w + batch];
    const float b2r = b2[16 * w + batch];
    f32x4 b3r8[8];
    #pragma unroll
    for (int jl = 0; jl < 8; ++jl)
        b3r8[jl] = *(const f32x4*)&b3[16 * (8 * jl + w) + 4 * g];

    // ---- z0 = a[:,0] @ W_init + b_init ; lane state h = 16*jl + 2*w + hb ----
    float zb[8], k1r[8], k2r[8], k3r[8];
    {
        const float* ap = coeffs + (size_t)(rowbase + batch) * (NINT * 32);
        float av[8];
        #pragma unroll
        for (int c = 0; c < 8; ++c) av[c] = ap[c];
        #pragma unroll
        for (int jl = 0; jl < 8; ++jl) {
            const int h = 16 * jl + 2 * w + hb;
            float z = b_init[h];
            #pragma unroll
            for (int c = 0; c < 8; ++c) z = fmaf(av[c], W_init[c * 128 + h], z);
            zb[jl] = z;
            if ((g & 1) == 0) Zs[batch * PITCH + h] = f2b(z);
        }
    }

    // ---- X'(t) register state: this lane's 4 channels chB..chB+3 ----
    const float* cpx = coeffs + (size_t)(rowbase + batch) * (NINT * 32) + chB;
    f32x4 bB  = *(const f32x4*)(cpx + 8);
    f32x4 tcv = *(const f32x4*)(cpx + 16);
    f32x4 tdv = *(const f32x4*)(cpx + 24);
    f32x4 xd0 = bB;                       // X'(0): interval 0, frac 0 -> b only

    const bf16x8* w3rv = (const bf16x8*)W3r_lds;
    __syncthreads();

    #pragma unroll 1
    for (int step = 0; step < NINT; ++step) {
        // prefetch next step's coeffs (clamped; hidden under stage 0)
        const int nxt = (step + 1 < NINT) ? step + 1 : NINT - 1;
        const float* cn = cpx + nxt * 32;
        const f32x4 nbB = *(const f32x4*)(cn + 8);
        const f32x4 ntc = *(const f32x4*)(cn + 16);
        const f32x4 ntd = *(const f32x4*)(cn + 24);

        STAGE_BODY(0, xd0)

        f32x4 xd1, xd2, xd3;
        #pragma unroll
        for (int i = 0; i < 4; ++i) {
            xd1[i] = bB[i] + (tcv[i] + tdv[i] * (1.0f/3.0f)) * (1.0f/3.0f);
            xd2[i] = bB[i] + (tcv[i] + tdv[i] * (2.0f/3.0f)) * (2.0f/3.0f);
            xd3[i] = bB[i] + tcv[i] + tdv[i];
        }

        STAGE_BODY(1, xd1)
        STAGE_BODY(2, xd2)
        STAGE_BODY(3, xd3)

        xd0 = xd3;                        // X' at frac 1 == next step's stage-0 X'
        bB = nbB; tcv = ntc; tdv = ntd;
    }

    // ---- epilogue: out = zT @ W_out + b_out ----
    if ((g & 1) == 0) {
        float prt = 0.0f;
        #pragma unroll
        for (int jl = 0; jl < 8; ++jl)
            prt = fmaf(zb[jl], W_out[16 * jl + 2 * w + hb], prt);
        Outp[2 * w + hb][batch] = prt;
    }
    __syncthreads();
    if (tid < 16) {
        float s = b_out[0];
        #pragma unroll
        for (int p = 0; p < 16; ++p) s += Outp[p][tid];
        out[rowbase + tid] = s;
    }
}

extern "C" void kernel_launch(void* const* d_in, const int* in_sizes, int n_in,
                              void* d_out, int out_size, void* d_ws, size_t ws_size,
                              hipStream_t stream) {
    const float* coeffs = (const float*)d_in[0];
    const float* W_init = (const float*)d_in[1];
    const float* b_init = (const float*)d_in[2];
    const float* W1     = (const float*)d_in[3];
    const float* b1     = (const float*)d_in[4];
    const float* W2     = (const float*)d_in[5];
    const float* b2     = (const float*)d_in[6];
    const float* W3     = (const float*)d_in[7];
    const float* b3     = (const float*)d_in[8];
    const float* W_out  = (const float*)d_in[9];
    const float* b_out  = (const float*)d_in[10];
    float* outp = (float*)d_out;

    unsigned short* w1f = (unsigned short*)d_ws;            // 32 KB
    unsigned short* w2f = w1f + 16384;                      // 32 KB
    unsigned short* w3f = w2f + 16384;                      // 256 KB

    hipLaunchKernelGGL(prep_frags, dim3(512), dim3(256), 0, stream, W1, W2, W3, w1f, w2f, w3f);
    hipLaunchKernelGGL(cde_mfma, dim3(4096 / BM), dim3(512), 0, stream,
                       coeffs, W_init, b_init, b1, b2, b3, W_out, b_out,
                       w1f, w2f, w3f, outp);
}